// Round 1
// baseline (383.671 us; speedup 1.0000x reference)
//
#include <hip/hip_runtime.h>

#define INTERVAL 0.5f

__device__ __forceinline__ float fast_softplus(float x) {
    // softplus(x) = max(x,0) + log1p(exp(-|x|))  (stable for both tails)
    float e = __expf(-fabsf(x));
    return fmaxf(x, 0.0f) + log1pf(e);
}

__device__ __forceinline__ float fast_sigmoid(float x) {
    return 1.0f / (1.0f + __expf(-x));
}

// One wave64 per ray. ray_id is sorted, so each ray's samples are a
// contiguous slice [start, end). Segmented exclusive scan of log(1-alpha)
// done with wave shuffles; carry accumulates across 64-sample chunks.
__global__ __launch_bounds__(256) void favor_render_kernel(
    const float* __restrict__ density,
    const float* __restrict__ rgb_feat,   // [M,3]
    const float* __restrict__ shift,      // [1]
    const int*   __restrict__ ray_id,     // [M], sorted
    int M, int N,
    float* __restrict__ weights,          // [M]
    float* __restrict__ alphainv_last,    // [N]
    float* __restrict__ out3)             // [N,3]
{
    const int wave = (blockIdx.x * blockDim.x + threadIdx.x) >> 6;
    const int t    = threadIdx.x & 63;
    if (wave >= N) return;
    const int ray = wave;

    // Segment bounds: lower_bound(ray) and lower_bound(ray+1).
    // All lanes search (lane 0 -> ray, others -> ray+1), broadcast results.
    {
        // nothing
    }
    int target = ray + (t ? 1 : 0);
    int lo = 0, hi = M;
    while (lo < hi) {
        int mid = (lo + hi) >> 1;
        if (ray_id[mid] < target) lo = mid + 1; else hi = mid;
    }
    const int start = __shfl(lo, 0);
    const int end   = __shfl(lo, 1);

    const float sh = shift[0];

    float carry = 0.0f;                 // running sum of log(1-alpha) for this ray
    float acc0 = 0.0f, acc1 = 0.0f, acc2 = 0.0f;

    for (int base = start; base < end; base += 64) {
        const int i = base + t;
        const bool valid = (i < end);

        float d = valid ? density[i] : 0.0f;
        float l = -INTERVAL * fast_softplus(d + sh);   // log(1 - alpha)
        float lv = valid ? l : 0.0f;

        // inclusive wave scan of lv
        float scan = lv;
        #pragma unroll
        for (int off = 1; off < 64; off <<= 1) {
            float y = __shfl_up(scan, off);
            if (t >= off) scan += y;
        }
        const float tot  = __shfl(scan, 63);
        const float excl = scan - lv;

        const float T     = __expf(carry + excl);      // transmittance before sample
        const float alpha = 1.0f - __expf(l);
        const float w     = alpha * T;

        if (valid) {
            weights[i] = w;
            const float r = rgb_feat[3 * i + 0];
            const float g = rgb_feat[3 * i + 1];
            const float b = rgb_feat[3 * i + 2];
            acc0 += w * fast_sigmoid(r);
            acc1 += w * fast_sigmoid(g);
            acc2 += w * fast_sigmoid(b);
        }
        carry += tot;
    }

    // wave reduction of rgb accumulators
    #pragma unroll
    for (int off = 32; off > 0; off >>= 1) {
        acc0 += __shfl_down(acc0, off);
        acc1 += __shfl_down(acc1, off);
        acc2 += __shfl_down(acc2, off);
    }

    if (t == 0) {
        const float ainv = __expf(carry);              // leftover transmittance
        alphainv_last[ray] = ainv;
        out3[3 * ray + 0] = acc0 + ainv;
        out3[3 * ray + 1] = acc1 + ainv;
        out3[3 * ray + 2] = acc2 + ainv;
    }
}

extern "C" void kernel_launch(void* const* d_in, const int* in_sizes, int n_in,
                              void* d_out, int out_size, void* d_ws, size_t ws_size,
                              hipStream_t stream) {
    const float* density  = (const float*)d_in[0];
    const float* rgb_feat = (const float*)d_in[1];
    const float* shift    = (const float*)d_in[2];
    const int*   ray_id   = (const int*)d_in[3];

    const int M = in_sizes[0];
    const int N = (out_size - M) / 4;   // out_size = M + N + 3N

    float* weights       = (float*)d_out;
    float* alphainv_last = weights + M;
    float* out3          = alphainv_last + N;

    const int block = 256;                      // 4 waves per block
    const int waves_per_block = block / 64;
    const int grid = (N + waves_per_block - 1) / waves_per_block;

    favor_render_kernel<<<grid, block, 0, stream>>>(
        density, rgb_feat, shift, ray_id, M, N,
        weights, alphainv_last, out3);
}

// Round 2
// 247.653 us; speedup vs baseline: 1.5492x; 1.5492x over previous
//
#include <hip/hip_runtime.h>

#define INTERVAL 0.5f

__device__ __forceinline__ float cheap_softplus(float x) {
    // softplus(x) = max(x,0) + log(1 + exp(-|x|)); hw exp/log, abs err ~1e-7
    float e = __expf(-fabsf(x));
    return fmaxf(x, 0.0f) + __logf(1.0f + e);
}

__device__ __forceinline__ float fast_sigmoid(float x) {
    return 1.0f / (1.0f + __expf(-x));
}

// Pass 1: segment-start detection over sorted ray_id (coalesced).
// starts[r] = first sample index with ray_id >= r, for r in [0, N]; starts[N] = M.
__global__ __launch_bounds__(256) void seg_starts_kernel(
    const int* __restrict__ ray_id, int M, int N, int* __restrict__ starts)
{
    const int i = blockIdx.x * blockDim.x + threadIdx.x;
    if (i >= M) return;
    const int cur  = ray_id[i];
    const int prev = (i == 0) ? -1 : ray_id[i - 1];
    for (int r = prev + 1; r <= cur; ++r) starts[r] = i;
    if (i == M - 1) {
        for (int r = cur + 1; r <= N; ++r) starts[r] = M;
    }
}

// Pass 2: one wave64 per ray. Segment bounds come from starts[]; segmented
// exclusive scan of log(1-alpha) via wave shuffles, carry across 64-chunks.
__global__ __launch_bounds__(256) void favor_render_kernel(
    const float* __restrict__ density,
    const float* __restrict__ rgb_feat,   // [M,3]
    const float* __restrict__ shift,      // [1]
    const int*   __restrict__ starts,     // [N+1]
    int M, int N,
    float* __restrict__ weights,          // [M]
    float* __restrict__ alphainv_last,    // [N]
    float* __restrict__ out3)             // [N,3]
{
    const int wave = (blockIdx.x * blockDim.x + threadIdx.x) >> 6;
    const int t    = threadIdx.x & 63;
    if (wave >= N) return;
    const int ray = wave;

    const int start = starts[ray];
    const int end   = starts[ray + 1];

    const float sh = shift[0];

    float carry = 0.0f;                 // running sum of log(1-alpha) for this ray
    float acc0 = 0.0f, acc1 = 0.0f, acc2 = 0.0f;

    for (int base = start; base < end; base += 64) {
        const int i = base + t;
        const bool valid = (i < end);

        float d  = valid ? density[i] : 0.0f;
        float l  = -INTERVAL * cheap_softplus(d + sh);   // log(1 - alpha)
        float lv = valid ? l : 0.0f;

        // inclusive wave scan of lv
        float scan = lv;
        #pragma unroll
        for (int off = 1; off < 64; off <<= 1) {
            float y = __shfl_up(scan, off);
            scan += (t >= off) ? y : 0.0f;
        }
        const float tot  = __shfl(scan, 63);
        const float excl = scan - lv;

        // w = alpha * T = exp(carry+excl) - exp(carry+excl+l)
        const float Te = __expf(carry + excl);
        const float Ti = __expf(carry + excl + l);
        const float w  = Te - Ti;

        if (valid) {
            weights[i] = w;
            const float r = rgb_feat[3 * i + 0];
            const float g = rgb_feat[3 * i + 1];
            const float b = rgb_feat[3 * i + 2];
            acc0 += w * fast_sigmoid(r);
            acc1 += w * fast_sigmoid(g);
            acc2 += w * fast_sigmoid(b);
        }
        carry += tot;
    }

    // wave reduction of rgb accumulators
    #pragma unroll
    for (int off = 32; off > 0; off >>= 1) {
        acc0 += __shfl_down(acc0, off);
        acc1 += __shfl_down(acc1, off);
        acc2 += __shfl_down(acc2, off);
    }

    if (t == 0) {
        const float ainv = __expf(carry);              // leftover transmittance
        alphainv_last[ray] = ainv;
        out3[3 * ray + 0] = acc0 + ainv;
        out3[3 * ray + 1] = acc1 + ainv;
        out3[3 * ray + 2] = acc2 + ainv;
    }
}

// Fallback (no workspace): original binary-search variant.
__global__ __launch_bounds__(256) void favor_render_bsearch_kernel(
    const float* __restrict__ density,
    const float* __restrict__ rgb_feat,
    const float* __restrict__ shift,
    const int*   __restrict__ ray_id,
    int M, int N,
    float* __restrict__ weights,
    float* __restrict__ alphainv_last,
    float* __restrict__ out3)
{
    const int wave = (blockIdx.x * blockDim.x + threadIdx.x) >> 6;
    const int t    = threadIdx.x & 63;
    if (wave >= N) return;
    const int ray = wave;

    int target = ray + (t ? 1 : 0);
    int lo = 0, hi = M;
    while (lo < hi) {
        int mid = (lo + hi) >> 1;
        if (ray_id[mid] < target) lo = mid + 1; else hi = mid;
    }
    const int start = __shfl(lo, 0);
    const int end   = __shfl(lo, 1);

    const float sh = shift[0];
    float carry = 0.0f, acc0 = 0.0f, acc1 = 0.0f, acc2 = 0.0f;

    for (int base = start; base < end; base += 64) {
        const int i = base + t;
        const bool valid = (i < end);
        float d  = valid ? density[i] : 0.0f;
        float l  = -INTERVAL * cheap_softplus(d + sh);
        float lv = valid ? l : 0.0f;
        float scan = lv;
        #pragma unroll
        for (int off = 1; off < 64; off <<= 1) {
            float y = __shfl_up(scan, off);
            scan += (t >= off) ? y : 0.0f;
        }
        const float tot  = __shfl(scan, 63);
        const float excl = scan - lv;
        const float Te = __expf(carry + excl);
        const float Ti = __expf(carry + excl + l);
        const float w  = Te - Ti;
        if (valid) {
            weights[i] = w;
            acc0 += w * fast_sigmoid(rgb_feat[3 * i + 0]);
            acc1 += w * fast_sigmoid(rgb_feat[3 * i + 1]);
            acc2 += w * fast_sigmoid(rgb_feat[3 * i + 2]);
        }
        carry += tot;
    }
    #pragma unroll
    for (int off = 32; off > 0; off >>= 1) {
        acc0 += __shfl_down(acc0, off);
        acc1 += __shfl_down(acc1, off);
        acc2 += __shfl_down(acc2, off);
    }
    if (t == 0) {
        const float ainv = __expf(carry);
        alphainv_last[ray] = ainv;
        out3[3 * ray + 0] = acc0 + ainv;
        out3[3 * ray + 1] = acc1 + ainv;
        out3[3 * ray + 2] = acc2 + ainv;
    }
}

extern "C" void kernel_launch(void* const* d_in, const int* in_sizes, int n_in,
                              void* d_out, int out_size, void* d_ws, size_t ws_size,
                              hipStream_t stream) {
    const float* density  = (const float*)d_in[0];
    const float* rgb_feat = (const float*)d_in[1];
    const float* shift    = (const float*)d_in[2];
    const int*   ray_id   = (const int*)d_in[3];

    const int M = in_sizes[0];
    const int N = (out_size - M) / 4;   // out_size = M + N + 3N

    float* weights       = (float*)d_out;
    float* alphainv_last = weights + M;
    float* out3          = alphainv_last + N;

    const int block = 256;
    const int grid_render = (N * 64 + block - 1) / block;

    const size_t starts_bytes = (size_t)(N + 1) * sizeof(int);
    if (ws_size >= starts_bytes) {
        int* starts = (int*)d_ws;
        const int grid_starts = (M + block - 1) / block;
        seg_starts_kernel<<<grid_starts, block, 0, stream>>>(ray_id, M, N, starts);
        favor_render_kernel<<<grid_render, block, 0, stream>>>(
            density, rgb_feat, shift, starts, M, N,
            weights, alphainv_last, out3);
    } else {
        favor_render_bsearch_kernel<<<grid_render, block, 0, stream>>>(
            density, rgb_feat, shift, ray_id, M, N,
            weights, alphainv_last, out3);
    }
}

// Round 3
// 223.600 us; speedup vs baseline: 1.7159x; 1.1076x over previous
//
#include <hip/hip_runtime.h>

#define INTERVAL 0.5f

__device__ __forceinline__ float cheap_softplus(float x) {
    // softplus(x) = max(x,0) + log(1 + exp(-|x|)); hw exp/log, abs err ~1e-7
    float e = __expf(-fabsf(x));
    return fmaxf(x, 0.0f) + __logf(1.0f + e);
}

__device__ __forceinline__ float fast_sigmoid(float x) {
    return 1.0f / (1.0f + __expf(-x));
}

// DPP-based wave64 inclusive add-scan (LLVM AtomicOptimizer sequence):
// row_shr 1/2/4/8 (per-16-row scan), row_bcast:15 (rows 1,3), row_bcast:31
// (rows 2,3). All VALU-pipe, ~4cyc latency each vs ~100+ for ds_bpermute.
#define DPP_ADD(x, ctrl, rmask)                                               \
    do {                                                                      \
        int _s = __builtin_amdgcn_update_dpp(0, __float_as_int(x), (ctrl),    \
                                             (rmask), 0xf, true);             \
        (x) += __int_as_float(_s);                                            \
    } while (0)

__device__ __forceinline__ float wave_inclusive_scan(float x) {
    DPP_ADD(x, 0x111, 0xf);  // row_shr:1
    DPP_ADD(x, 0x112, 0xf);  // row_shr:2
    DPP_ADD(x, 0x114, 0xf);  // row_shr:4
    DPP_ADD(x, 0x118, 0xf);  // row_shr:8
    DPP_ADD(x, 0x142, 0xa);  // row_bcast:15 -> rows 1,3
    DPP_ADD(x, 0x143, 0xc);  // row_bcast:31 -> rows 2,3
    return x;
}

__device__ __forceinline__ float bcast_lane63(float x) {
    return __int_as_float(__builtin_amdgcn_readlane(__float_as_int(x), 63));
}

// Pass 1: segment-start detection over sorted ray_id (coalesced).
__global__ __launch_bounds__(256) void seg_starts_kernel(
    const int* __restrict__ ray_id, int M, int N, int* __restrict__ starts)
{
    const int i = blockIdx.x * blockDim.x + threadIdx.x;
    if (i >= M) return;
    const int cur  = ray_id[i];
    const int prev = (i == 0) ? -1 : ray_id[i - 1];
    for (int r = prev + 1; r <= cur; ++r) starts[r] = i;
    if (i == M - 1) {
        for (int r = cur + 1; r <= N; ++r) starts[r] = M;
    }
}

// Pass 2: one wave64 per ray, 128 samples per iteration (2 chunks with
// independent DPP scans; loads for both chunks issue up front).
__global__ __launch_bounds__(256) void favor_render_kernel(
    const float* __restrict__ density,
    const float* __restrict__ rgb_feat,   // [M,3]
    const float* __restrict__ shift,      // [1]
    const int*   __restrict__ starts,     // [N+1]
    int M, int N,
    float* __restrict__ weights,          // [M]
    float* __restrict__ alphainv_last,    // [N]
    float* __restrict__ out3)             // [N,3]
{
    const int wave = (blockIdx.x * blockDim.x + threadIdx.x) >> 6;
    const int t    = threadIdx.x & 63;
    if (wave >= N) return;
    const int ray = wave;

    const int start = starts[ray];
    const int end   = starts[ray + 1];

    const float sh = shift[0];

    float carry = 0.0f;
    float acc0 = 0.0f, acc1 = 0.0f, acc2 = 0.0f;

    for (int base = start; base < end; base += 128) {
        const int i0 = base + t;
        const int i1 = i0 + 64;
        const bool v0 = (i0 < end);
        const bool v1 = (i1 < end);
        const bool any1 = (base + 64) < end;   // wave-uniform

        // unconditional clamped loads -> compiler can issue them all up front
        const int c0 = min(i0, end - 1);
        float d0 = density[c0];
        float r0 = rgb_feat[3 * c0 + 0];
        float g0 = rgb_feat[3 * c0 + 1];
        float b0 = rgb_feat[3 * c0 + 2];

        float d1 = 0.0f, r1 = 0.0f, g1 = 0.0f, b1 = 0.0f;
        if (any1) {
            const int c1 = min(i1, end - 1);
            d1 = density[c1];
            r1 = rgb_feat[3 * c1 + 0];
            g1 = rgb_feat[3 * c1 + 1];
            b1 = rgb_feat[3 * c1 + 2];
        }

        const float l0  = -INTERVAL * cheap_softplus(d0 + sh);
        const float l1  = -INTERVAL * cheap_softplus(d1 + sh);
        const float lv0 = v0 ? l0 : 0.0f;
        const float lv1 = v1 ? l1 : 0.0f;

        // two independent DPP scan chains (2x ILP)
        const float s0 = wave_inclusive_scan(lv0);
        const float s1 = wave_inclusive_scan(lv1);
        const float tot0 = bcast_lane63(s0);
        const float tot1 = bcast_lane63(s1);

        const float e0 = carry + (s0 - lv0);
        const float e1 = carry + tot0 + (s1 - lv1);

        // w = alpha*T = exp(log T) - exp(log T + log(1-alpha))
        const float w0 = __expf(e0) - __expf(e0 + l0);
        const float w1 = __expf(e1) - __expf(e1 + l1);

        if (v0) {
            weights[i0] = w0;
            acc0 += w0 * fast_sigmoid(r0);
            acc1 += w0 * fast_sigmoid(g0);
            acc2 += w0 * fast_sigmoid(b0);
        }
        if (v1) {
            weights[i1] = w1;
            acc0 += w1 * fast_sigmoid(r1);
            acc1 += w1 * fast_sigmoid(g1);
            acc2 += w1 * fast_sigmoid(b1);
        }
        carry += tot0 + tot1;
    }

    // wave totals via DPP scan + readlane (VALU-only epilogue reduction)
    const float s_acc0 = bcast_lane63(wave_inclusive_scan(acc0));
    const float s_acc1 = bcast_lane63(wave_inclusive_scan(acc1));
    const float s_acc2 = bcast_lane63(wave_inclusive_scan(acc2));

    if (t == 0) {
        const float ainv = __expf(carry);
        alphainv_last[ray] = ainv;
        out3[3 * ray + 0] = s_acc0 + ainv;
        out3[3 * ray + 1] = s_acc1 + ainv;
        out3[3 * ray + 2] = s_acc2 + ainv;
    }
}

extern "C" void kernel_launch(void* const* d_in, const int* in_sizes, int n_in,
                              void* d_out, int out_size, void* d_ws, size_t ws_size,
                              hipStream_t stream) {
    const float* density  = (const float*)d_in[0];
    const float* rgb_feat = (const float*)d_in[1];
    const float* shift    = (const float*)d_in[2];
    const int*   ray_id   = (const int*)d_in[3];

    const int M = in_sizes[0];
    const int N = (out_size - M) / 4;   // out_size = M + N + 3N

    float* weights       = (float*)d_out;
    float* alphainv_last = weights + M;
    float* out3          = alphainv_last + N;

    const int block = 256;
    int* starts = (int*)d_ws;

    const int grid_starts = (M + block - 1) / block;
    seg_starts_kernel<<<grid_starts, block, 0, stream>>>(ray_id, M, N, starts);

    const int grid_render = (N * 64 + block - 1) / block;
    favor_render_kernel<<<grid_render, block, 0, stream>>>(
        density, rgb_feat, shift, starts, M, N,
        weights, alphainv_last, out3);
}

// Round 4
// 220.813 us; speedup vs baseline: 1.7375x; 1.0126x over previous
//
#include <hip/hip_runtime.h>

// 1 - alpha = (1 + exp(density+shift))^(-INTERVAL), INTERVAL = 0.5 exactly
// => a = rsqrt(1 + exp(x)); 1/a = u*a; alpha/a = u*a - 1.

__device__ __forceinline__ float fast_sigmoid(float x) {
    return __builtin_amdgcn_rcpf(1.0f + __expf(-x));
}

// ---- DPP wave64 scans ------------------------------------------------------
// Additive (identity 0, bound_ctrl=true -> 0 for invalid lanes)
#define DPP_ADD(x, ctrl, rmask)                                               \
    do {                                                                      \
        int _s = __builtin_amdgcn_update_dpp(0, __float_as_int(x), (ctrl),    \
                                             (rmask), 0xf, true);             \
        (x) += __int_as_float(_s);                                            \
    } while (0)

// Multiplicative (identity 1.0 via old-operand, bound_ctrl=false)
#define DPP_MUL(x, ctrl, rmask)                                               \
    do {                                                                      \
        int _s = __builtin_amdgcn_update_dpp(0x3f800000, __float_as_int(x),   \
                                             (ctrl), (rmask), 0xf, false);    \
        (x) *= __int_as_float(_s);                                            \
    } while (0)

__device__ __forceinline__ float wave_scan_add(float x) {
    DPP_ADD(x, 0x111, 0xf);  // row_shr:1
    DPP_ADD(x, 0x112, 0xf);  // row_shr:2
    DPP_ADD(x, 0x114, 0xf);  // row_shr:4
    DPP_ADD(x, 0x118, 0xf);  // row_shr:8
    DPP_ADD(x, 0x142, 0xa);  // row_bcast:15 -> rows 1,3
    DPP_ADD(x, 0x143, 0xc);  // row_bcast:31 -> rows 2,3
    return x;
}

__device__ __forceinline__ float wave_scan_mul(float x) {
    DPP_MUL(x, 0x111, 0xf);
    DPP_MUL(x, 0x112, 0xf);
    DPP_MUL(x, 0x114, 0xf);
    DPP_MUL(x, 0x118, 0xf);
    DPP_MUL(x, 0x142, 0xa);
    DPP_MUL(x, 0x143, 0xc);
    return x;
}

__device__ __forceinline__ float bcast_lane63(float x) {
    return __int_as_float(__builtin_amdgcn_readlane(__float_as_int(x), 63));
}

// ---- Pass 1: segment starts (int4-vectorized boundary detection) -----------
__global__ __launch_bounds__(256) void seg_starts4_kernel(
    const int4* __restrict__ ray4, int M4, int M, int N,
    const int* __restrict__ ray_id, int* __restrict__ starts)
{
    const int i = blockIdx.x * blockDim.x + threadIdx.x;
    if (i >= M4) return;
    const int4 v = ray4[i];
    const int prev = (i == 0) ? -1 : ray_id[4 * i - 1];
    const int base = 4 * i;
    for (int r = prev + 1; r <= v.x; ++r) starts[r] = base;
    for (int r = v.x + 1;  r <= v.y; ++r) starts[r] = base + 1;
    for (int r = v.y + 1;  r <= v.z; ++r) starts[r] = base + 2;
    for (int r = v.z + 1;  r <= v.w; ++r) starts[r] = base + 3;
    if (i == M4 - 1) {
        int last = v.w;
        for (int j = 4 * M4; j < M; ++j) {      // scalar tail (M%4)
            const int cur = ray_id[j];
            for (int r = last + 1; r <= cur; ++r) starts[r] = j;
            last = cur;
        }
        for (int r = last + 1; r <= N; ++r) starts[r] = M;
    }
}

// ---- Pass 2: one wave64 per ray --------------------------------------------
__global__ __launch_bounds__(256) void favor_render_kernel(
    const float* __restrict__ density,
    const float* __restrict__ rgb_feat,   // [M,3]
    const float* __restrict__ shift,      // [1]
    const int*   __restrict__ starts,     // [N+1]
    int M, int N,
    float* __restrict__ weights,          // [M]
    float* __restrict__ alphainv_last,    // [N]
    float* __restrict__ out3)             // [N,3]
{
    const int wave = (blockIdx.x * blockDim.x + threadIdx.x) >> 6;
    const int t    = threadIdx.x & 63;
    if (wave >= N) return;
    const int ray = wave;

    const int start = starts[ray];
    const int end   = starts[ray + 1];

    const float sh = shift[0];

    float carryT = 1.0f;                  // running transmittance (product of a)
    float acc0 = 0.0f, acc1 = 0.0f, acc2 = 0.0f;

    for (int base = start; base < end; base += 128) {
        const int i0 = base + t;
        const int i1 = i0 + 64;
        const bool v0 = (i0 < end);
        const bool v1 = (i1 < end);
        const bool any1 = (base + 64) < end;   // wave-uniform

        // issue all loads up front (clamped; L2/L3-resident)
        const int c0 = min(i0, end - 1);
        const float d0 = density[c0];
        const float r0 = rgb_feat[3 * c0 + 0];
        const float g0 = rgb_feat[3 * c0 + 1];
        const float b0 = rgb_feat[3 * c0 + 2];
        float d1 = 0.0f, r1 = 0.0f, g1 = 0.0f, b1 = 0.0f;
        if (any1) {
            const int c1 = min(i1, end - 1);
            d1 = density[c1];
            r1 = rgb_feat[3 * c1 + 0];
            g1 = rgb_feat[3 * c1 + 1];
            b1 = rgb_feat[3 * c1 + 2];
        }

        // chunk 0
        const float u0 = 1.0f + __expf(d0 + sh);
        const float a0 = __builtin_amdgcn_rsqf(u0);     // 1 - alpha
        const float m0 = v0 ? a0 : 1.0f;
        const float s0 = wave_scan_mul(m0);             // inclusive product
        const float tot0 = bcast_lane63(s0);
        const float Ti0  = carryT * s0;                 // T including own a
        const float w0   = Ti0 * (u0 * a0 - 1.0f);      // T_excl * alpha
        if (v0) {
            weights[i0] = w0;
            acc0 += w0 * fast_sigmoid(r0);
            acc1 += w0 * fast_sigmoid(g0);
            acc2 += w0 * fast_sigmoid(b0);
        }

        if (any1) {
            const float u1 = 1.0f + __expf(d1 + sh);
            const float a1 = __builtin_amdgcn_rsqf(u1);
            const float m1 = v1 ? a1 : 1.0f;
            const float s1 = wave_scan_mul(m1);
            const float tot1 = bcast_lane63(s1);
            const float Ti1  = carryT * tot0 * s1;
            const float w1   = Ti1 * (u1 * a1 - 1.0f);
            if (v1) {
                weights[i1] = w1;
                acc0 += w1 * fast_sigmoid(r1);
                acc1 += w1 * fast_sigmoid(g1);
                acc2 += w1 * fast_sigmoid(b1);
            }
            carryT *= tot0 * tot1;
        } else {
            carryT *= tot0;
        }
    }

    // wave totals (VALU-only epilogue reduction)
    const float s_acc0 = bcast_lane63(wave_scan_add(acc0));
    const float s_acc1 = bcast_lane63(wave_scan_add(acc1));
    const float s_acc2 = bcast_lane63(wave_scan_add(acc2));

    if (t == 0) {
        const float ainv = carryT;                     // leftover transmittance
        alphainv_last[ray] = ainv;
        out3[3 * ray + 0] = s_acc0 + ainv;
        out3[3 * ray + 1] = s_acc1 + ainv;
        out3[3 * ray + 2] = s_acc2 + ainv;
    }
}

extern "C" void kernel_launch(void* const* d_in, const int* in_sizes, int n_in,
                              void* d_out, int out_size, void* d_ws, size_t ws_size,
                              hipStream_t stream) {
    const float* density  = (const float*)d_in[0];
    const float* rgb_feat = (const float*)d_in[1];
    const float* shift    = (const float*)d_in[2];
    const int*   ray_id   = (const int*)d_in[3];

    const int M = in_sizes[0];
    const int N = (out_size - M) / 4;   // out_size = M + N + 3N

    float* weights       = (float*)d_out;
    float* alphainv_last = weights + M;
    float* out3          = alphainv_last + N;

    const int block = 256;
    int* starts = (int*)d_ws;

    const int M4 = M >> 2;
    const int grid_starts = (M4 + block - 1) / block;
    seg_starts4_kernel<<<grid_starts, block, 0, stream>>>(
        (const int4*)ray_id, M4, M, N, ray_id, starts);

    const int grid_render = (N * 64 + block - 1) / block;
    favor_render_kernel<<<grid_render, block, 0, stream>>>(
        density, rgb_feat, shift, starts, M, N,
        weights, alphainv_last, out3);
}

// Round 5
// 214.055 us; speedup vs baseline: 1.7924x; 1.0316x over previous
//
#include <hip/hip_runtime.h>

// 1 - alpha = (1 + exp(density+shift))^(-0.5) = rsqrt(u), u = 1 + exp(x).
// alpha * (1/(1-alpha)) = u*a - 1, so w = T_incl * (u*a - 1).

__device__ __forceinline__ float fast_sigmoid(float x) {
    return __builtin_amdgcn_rcpf(1.0f + __expf(-x));
}

// ---- DPP wave64 scans ------------------------------------------------------
#define DPP_ADD(x, ctrl, rmask)                                               \
    do {                                                                      \
        int _s = __builtin_amdgcn_update_dpp(0, __float_as_int(x), (ctrl),    \
                                             (rmask), 0xf, true);             \
        (x) += __int_as_float(_s);                                            \
    } while (0)

#define DPP_MUL(x, ctrl, rmask)                                               \
    do {                                                                      \
        int _s = __builtin_amdgcn_update_dpp(0x3f800000, __float_as_int(x),   \
                                             (ctrl), (rmask), 0xf, false);    \
        (x) *= __int_as_float(_s);                                            \
    } while (0)

__device__ __forceinline__ float wave_scan_add(float x) {
    DPP_ADD(x, 0x111, 0xf);  // row_shr:1
    DPP_ADD(x, 0x112, 0xf);  // row_shr:2
    DPP_ADD(x, 0x114, 0xf);  // row_shr:4
    DPP_ADD(x, 0x118, 0xf);  // row_shr:8
    DPP_ADD(x, 0x142, 0xa);  // row_bcast:15 -> rows 1,3
    DPP_ADD(x, 0x143, 0xc);  // row_bcast:31 -> rows 2,3
    return x;
}

__device__ __forceinline__ float wave_scan_mul(float x) {
    DPP_MUL(x, 0x111, 0xf);
    DPP_MUL(x, 0x112, 0xf);
    DPP_MUL(x, 0x114, 0xf);
    DPP_MUL(x, 0x118, 0xf);
    DPP_MUL(x, 0x142, 0xa);
    DPP_MUL(x, 0x143, 0xc);
    return x;
}

__device__ __forceinline__ float bcast_lane63(float x) {
    return __int_as_float(__builtin_amdgcn_readlane(__float_as_int(x), 63));
}

// ---- Pass 1: segment starts (int4-vectorized boundary detection) -----------
__global__ __launch_bounds__(256) void seg_starts4_kernel(
    const int4* __restrict__ ray4, int M4, int M, int N,
    const int* __restrict__ ray_id, int* __restrict__ starts)
{
    const int i = blockIdx.x * blockDim.x + threadIdx.x;
    if (i >= M4) return;
    const int4 v = ray4[i];
    const int prev = (i == 0) ? -1 : ray_id[4 * i - 1];
    const int base = 4 * i;
    for (int r = prev + 1; r <= v.x; ++r) starts[r] = base;
    for (int r = v.x + 1;  r <= v.y; ++r) starts[r] = base + 1;
    for (int r = v.y + 1;  r <= v.z; ++r) starts[r] = base + 2;
    for (int r = v.z + 1;  r <= v.w; ++r) starts[r] = base + 3;
    if (i == M4 - 1) {
        int last = v.w;
        for (int j = 4 * M4; j < M; ++j) {      // scalar tail (M%4)
            const int cur = ray_id[j];
            for (int r = last + 1; r <= cur; ++r) starts[r] = j;
            last = cur;
        }
        for (int r = last + 1; r <= N; ++r) starts[r] = M;
    }
}

// ---- Pass 2: RPW rays per wave, chunk-0 loads of all rays issued up front --
#define RPW 4

__global__ __launch_bounds__(256) void favor_render_kernel(
    const float* __restrict__ density,
    const float* __restrict__ rgb_feat,   // [M,3]
    const float* __restrict__ shift,      // [1]
    const int*   __restrict__ starts,     // [N+1]
    int M, int N,
    float* __restrict__ weights,          // [M]
    float* __restrict__ alphainv_last,    // [N]
    float* __restrict__ out3)             // [N,3]
{
    const int wave = (blockIdx.x * blockDim.x + threadIdx.x) >> 6;
    const int t    = threadIdx.x & 63;
    const int r0   = wave * RPW;
    if (r0 >= N) return;

    // Bounds for all RPW rays: one coalesced load, broadcast to SGPRs.
    const int bv = starts[min(r0 + t, N)];
    int s[RPW + 1];
    #pragma unroll
    for (int k = 0; k <= RPW; ++k)
        s[k] = __builtin_amdgcn_readlane(bv, k);

    const float sh = shift[0];

    // Issue chunk-0 loads for ALL rays before any compute (cross-ray MLP).
    float pd[RPW], pr[RPW], pg[RPW], pb[RPW];
    #pragma unroll
    for (int j = 0; j < RPW; ++j) {
        const int c = max(min(s[j] + t, s[j + 1] - 1), 0);
        pd[j] = density[c];
        pr[j] = rgb_feat[3 * c + 0];
        pg[j] = rgb_feat[3 * c + 1];
        pb[j] = rgb_feat[3 * c + 2];
    }

    // Fully unrolled: 4 independent ray computations the scheduler can
    // interleave (ILP substitutes for missing TLP).
    #pragma unroll
    for (int j = 0; j < RPW; ++j) {
        const int ray = r0 + j;
        if (ray >= N) continue;
        const int st = s[j], en = s[j + 1];

        float carryT = 1.0f;
        float a0 = 0.0f, a1 = 0.0f, a2 = 0.0f;

        // chunk 0 (prefetched)
        {
            const bool valid = (st + t) < en;
            const float u = 1.0f + __expf(pd[j] + sh);
            const float a = __builtin_amdgcn_rsqf(u);      // 1 - alpha
            const float m = valid ? a : 1.0f;
            const float S = wave_scan_mul(m);              // inclusive product
            const float tot = bcast_lane63(S);
            const float w = S * (u * a - 1.0f);            // T_excl * alpha
            if (valid) {
                weights[st + t] = w;
                a0 = w * fast_sigmoid(pr[j]);
                a1 = w * fast_sigmoid(pg[j]);
                a2 = w * fast_sigmoid(pb[j]);
            }
            carryT = tot;
        }

        // remaining chunks (~47% of rays have exactly one)
        for (int base = st + 64; base < en; base += 64) {
            const int i = base + t;
            const bool valid = i < en;
            const int c = min(i, en - 1);
            const float d = density[c];
            const float r = rgb_feat[3 * c + 0];
            const float g = rgb_feat[3 * c + 1];
            const float b = rgb_feat[3 * c + 2];
            const float u = 1.0f + __expf(d + sh);
            const float a = __builtin_amdgcn_rsqf(u);
            const float m = valid ? a : 1.0f;
            const float S = wave_scan_mul(m);
            const float tot = bcast_lane63(S);
            const float w = carryT * S * (u * a - 1.0f);
            if (valid) {
                weights[i] = w;
                a0 += w * fast_sigmoid(r);
                a1 += w * fast_sigmoid(g);
                a2 += w * fast_sigmoid(b);
            }
            carryT *= tot;
        }

        // per-ray epilogue (three independent DPP reduction chains)
        const float t0 = bcast_lane63(wave_scan_add(a0));
        const float t1 = bcast_lane63(wave_scan_add(a1));
        const float t2 = bcast_lane63(wave_scan_add(a2));
        if (t == 0) {
            alphainv_last[ray] = carryT;
            out3[3 * ray + 0] = t0 + carryT;
            out3[3 * ray + 1] = t1 + carryT;
            out3[3 * ray + 2] = t2 + carryT;
        }
    }
}

extern "C" void kernel_launch(void* const* d_in, const int* in_sizes, int n_in,
                              void* d_out, int out_size, void* d_ws, size_t ws_size,
                              hipStream_t stream) {
    const float* density  = (const float*)d_in[0];
    const float* rgb_feat = (const float*)d_in[1];
    const float* shift    = (const float*)d_in[2];
    const int*   ray_id   = (const int*)d_in[3];

    const int M = in_sizes[0];
    const int N = (out_size - M) / 4;   // out_size = M + N + 3N

    float* weights       = (float*)d_out;
    float* alphainv_last = weights + M;
    float* out3          = alphainv_last + N;

    const int block = 256;
    int* starts = (int*)d_ws;

    const int M4 = M >> 2;
    const int grid_starts = (M4 + block - 1) / block;
    seg_starts4_kernel<<<grid_starts, block, 0, stream>>>(
        (const int4*)ray_id, M4, M, N, ray_id, starts);

    const int n_waves = (N + RPW - 1) / RPW;
    const int grid_render = (n_waves * 64 + block - 1) / block;
    favor_render_kernel<<<grid_render, block, 0, stream>>>(
        density, rgb_feat, shift, starts, M, N,
        weights, alphainv_last, out3);
}